// Round 7
// baseline (112.175 us; speedup 1.0000x reference)
//
#include <hip/hip_runtime.h>

#define S_LEN 4096
#define B_SZ 8
#define KTOT 384            // M (256) + D (128)
#define CPROWS 544          // 8-elem rows per parity copy (zero-padded past 4096)
#define HN_OFF 8388608      // 8*4096*256

typedef __attribute__((ext_vector_type(8))) short short8;
typedef __attribute__((ext_vector_type(4))) float f32x4;

typedef const __attribute__((address_space(1))) unsigned int as1_u32;
typedef __attribute__((address_space(3))) unsigned int as3_u32;

__device__ __forceinline__ void gload16(const short* g, short* l) {
  __builtin_amdgcn_global_load_lds((as1_u32*)g, (as3_u32*)l, 16, 0, 0);
}

__device__ __forceinline__ short f2bf(float f) {
  union { float f; unsigned u; } v; v.f = f;
  unsigned r = v.u + 0x7FFFu + ((v.u >> 16) & 1u);
  return (short)(r >> 16);
}

// K1 fused prep (unchanged from round 6):
__global__ __launch_bounds__(256) void k_prep(const float* __restrict__ x,
                                              const float* __restrict__ Wu,
                                              const float* __restrict__ bu,
                                              const float* __restrict__ H,
                                              const float* __restrict__ Wh,
                                              short* __restrict__ mx,
                                              short* __restrict__ cp,
                                              short* __restrict__ Hb,
                                              short* __restrict__ wht) {
  int bx = blockIdx.x;
  if (bx >= 12360) {
    int j = (bx - 12360) * 256 + threadIdx.x;
    if (j < 256 * KTOT) {
      int n = j / KTOT, k = j % KTOT;
      wht[j] = f2bf(Wh[k * 256 + n]);
    }
    return;
  }
  if (bx >= 8264) {
    int i = (bx - 8264) * 256 + threadIdx.x;
    Hb[i] = f2bf(H[i]);
    return;
  }
  if (bx >= 8192) {
    int idx = (bx - 8192) * 256 + threadIdx.x;   // b(8)*p(8)*r(36)*j(8)
    if (idx < 18432) {
      int j = idx & 7;
      int r = 508 + ((idx >> 3) % 36);
      int rem = (idx >> 3) / 36;
      int p = rem & 7;
      int b = rem >> 3;
      int e = 8 * r + p + j;
      if (e >= S_LEN)
        cp[((size_t)(b * 8 + p) * CPROWS + r) * 8 + j] = 0;
    }
    return;
  }
  int row = bx * 4 + (threadIdx.x >> 6);   // b*4096 + t
  int l = threadIdx.x & 63;
  const float* xr = x + (size_t)row * 128;
  float x0 = xr[l], x1 = xr[l + 64];
  float s = x0 * Wu[l] + x1 * Wu[l + 64];
  #pragma unroll
  for (int m = 32; m >= 1; m >>= 1) s += __shfl_xor(s, m, 64);
  short* mrow = mx + (size_t)row * KTOT + 256;
  mrow[l]      = f2bf(x0);
  mrow[l + 64] = f2bf(x1);
  float v = s + bu[0];
  v = v > 0.0f ? v : 0.0f;
  short vb = f2bf(v);
  if (l < 8) {
    int t = row & (S_LEN - 1);
    int b = row >> 12;
    int e = (S_LEN - 1) - t;       // u_rev index of this element
    int p = l;
    if (e >= p) {
      int d = e - p;
      cp[((size_t)(b * 8 + p) * CPROWS + (d >> 3)) * 8 + (d & 7)] = vb;
    }
  }
}

// K2: Toeplitz GEMM, 128x128 tile, TWO 128-thread waves, wave tile 128(s)x64(q).
// Toeplitz A-dedup: frag(mf+2,ks+1)==frag(mf,ks) -> 10 A + 8 B ds_reads per
// 64 MFMAs (58 FLOP/LDS-byte vs 37.5 before). Ring-3 LDS (B 48KB + A 12KB),
// STAGE(c+2) issued AFTER the barrier (slot (c-1)%3's readers are behind it,
// lgkmcnt(0) drains their reads -> race-free, one barrier/chunk).
// Uniform 10 vmem loads/wave/chunk -> vmcnt(10) steady, 0 tail.
__global__ __launch_bounds__(128) void k_conv(const short* __restrict__ cp,
                                              const short* __restrict__ Hb,
                                              short* __restrict__ mx) {
  __shared__ __attribute__((aligned(16))) short Bt[3][128 * 64];  // 48 KB
  __shared__ __attribute__((aligned(16))) short Aw[3][32 * 64];   // 12 KB

  int i = blockIdx.x;                 // 512 blocks, LPT: st descending
  int st = 31 - (i >> 4);
  int rem = i & 15;
  int qt  = rem & 1;
  int b   = rem >> 1;
  int s0 = st << 7, q0 = qt << 7;

  int tid = threadIdx.x;
  int lane = tid & 63, wid = tid >> 6;   // 2 waves; wid = q-half
  int lm = lane & 15, kg = lane >> 4;
  int l3 = lane >> 3, l7 = lane & 7;
  int lm7 = lm & 7;

  // B staging: wave wid stages rows q0 + wid*64 + i*8 + l3 (i=0..7),
  // source col pre-swizzled (l7^l3) so linear LDS dest is XOR-swizzled.
  const short* bSrc = Hb + (size_t)(q0 + wid * 64 + l3) * S_LEN + ((l7 ^ l3) << 3);

  // A staging: rows asbase + 16*wid + 8*i + l3 (i=0..1), parity pre-permuted
  // (l7-l3)&7 -> rotation swizzle on linear dest.
  int asbase = 496 - 16 * st;
  const size_t aPar = (size_t)(b * 8 + ((l7 - l3) & 7)) * CPROWS * 8;
  const short* aSrc = cp + aPar + (size_t)(asbase + 16 * wid + l3) * 8;

  // A-frag swizzled read offsets: data unit u = dbase + adel; read at
  // sigma(u) = (u&~7)|((u+(u>>3))&7).
  int dbase = 127 - lm + 8 * kg;
  const int adel10[10] = {0, -16, -32, -48, -64, -80, -96, -112, 32, 16};
  int aof[10];
  #pragma unroll
  for (int ii = 0; ii < 10; ++ii) {
    int u = dbase + adel10[ii];
    aof[ii] = ((u & ~7) | ((u + (u >> 3)) & 7)) << 3;   // shorts
  }

  // B-frag offsets (per wave: q-half wid)
  int bRow = (wid * 64 + lm) * 64;
  int bof[8];
  #pragma unroll
  for (int nf = 0; nf < 4; ++nf)
    #pragma unroll
    for (int ks = 0; ks < 2; ++ks)
      bof[nf * 2 + ks] = bRow + nf * 1024 + (((ks << 5) + (kg << 3)) ^ (lm7 << 3));

  f32x4 acc[8][4];
  #pragma unroll
  for (int ii = 0; ii < 8; ++ii)
    #pragma unroll
    for (int jn = 0; jn < 4; ++jn)
      acc[ii][jn] = (f32x4){0.0f, 0.0f, 0.0f, 0.0f};

  int nchunks = 2 * st + 2;

  auto STAGE = [&](int cc, int slot) {
    #pragma unroll
    for (int ii = 0; ii < 8; ++ii)
      gload16(bSrc + (size_t)ii * 8 * S_LEN + cc * 64, &Bt[slot][(wid * 64 + ii * 8) * 64]);
    #pragma unroll
    for (int ii = 0; ii < 2; ++ii)
      gload16(aSrc + (size_t)(ii * 8) * 8 + cc * 64, &Aw[slot][(16 * wid + ii * 8) * 64]);
  };

  STAGE(0, 0);
  STAGE(1, 1);

  int cur = 0;                         // slot of chunk c; stage slot = (cur+2)%3
  for (int c = 0; c < nchunks; ++c) {
    if (c + 1 < nchunks) asm volatile("s_waitcnt vmcnt(10) lgkmcnt(0)\n\ts_barrier" ::: "memory");
    else                 asm volatile("s_waitcnt vmcnt(0) lgkmcnt(0)\n\ts_barrier" ::: "memory");
    if (c + 2 < nchunks) {
      int tg = (cur >= 1) ? (cur - 1) : 2;
      STAGE(c + 2, tg);
    }
    const short* AwB = &Aw[cur][0];
    const short* BtB = &Bt[cur][0];
    short8 Au[10];
    #pragma unroll
    for (int ii = 0; ii < 10; ++ii) Au[ii] = *(const short8*)(AwB + aof[ii]);
    short8 Bf[8];
    #pragma unroll
    for (int ii = 0; ii < 8; ++ii) Bf[ii] = *(const short8*)(BtB + bof[ii]);
    __builtin_amdgcn_s_setprio(1);
    #pragma unroll
    for (int nf = 0; nf < 4; ++nf)
      #pragma unroll
      for (int mf = 0; mf < 8; ++mf)
        acc[mf][nf] = __builtin_amdgcn_mfma_f32_16x16x32_bf16(Au[mf], Bf[nf * 2], acc[mf][nf], 0, 0, 0);
    #pragma unroll
    for (int nf = 0; nf < 4; ++nf)
      #pragma unroll
      for (int mf = 0; mf < 8; ++mf) {
        short8 a1 = (mf < 2) ? Au[8 + mf] : Au[mf - 2];
        acc[mf][nf] = __builtin_amdgcn_mfma_f32_16x16x32_bf16(a1, Bf[nf * 2 + 1], acc[mf][nf], 0, 0, 0);
      }
    __builtin_amdgcn_s_setprio(0);
    cur = (cur == 2) ? 0 : cur + 1;
  }

  // C/D layout: col = lane&15, row = (lane>>4)*4 + reg
  #pragma unroll
  for (int mf = 0; mf < 8; ++mf)
    #pragma unroll
    for (int nf = 0; nf < 4; ++nf)
      #pragma unroll
      for (int j = 0; j < 4; ++j) {
        int s = s0 + mf * 16 + kg * 4 + j;
        int q = q0 + wid * 64 + nf * 16 + lm;
        mx[(size_t)(b * S_LEN + s) * KTOT + q] = f2bf(acc[mf][nf][j]);
      }
}

// K3: h = relu(mx @ W_h + b_h); h_n extra write for s==4095 rows. (unchanged)
__global__ __launch_bounds__(256, 2) void k_gemm2(const short* __restrict__ mx,
                                                  const short* __restrict__ wht,
                                                  const float* __restrict__ bh,
                                                  float* __restrict__ out) {
  __shared__ __attribute__((aligned(16))) short At[4][128 * 64];  // 64 KB

  int idx = blockIdx.x;       // 512 = 256 row-tiles * 2 n-tiles
  int nt = idx & 1;
  int rt = idx >> 1;
  int R0 = rt << 7;

  int tid = threadIdx.x;
  int lane = tid & 63, wid = tid >> 6;
  int wr = wid >> 1, wc = wid & 1;
  int lm = lane & 15, kg = lane >> 4;
  int l3 = lane >> 3, l7 = lane & 7;
  int lm7 = lm & 7;

  const short* aSrc  = mx  + (size_t)(R0 + wid * 32 + l3) * KTOT + ((l7 ^ l3) << 3);
  const short* bBase = wht + (size_t)(nt * 128 + wc * 64 + lm) * KTOT + 8 * kg;

  int aRow = (wr * 64 + lm) * 64;
  int aof[8];
  #pragma unroll
  for (int f = 0; f < 4; ++f)
    #pragma unroll
    for (int ks = 0; ks < 2; ++ks)
      aof[f * 2 + ks] = aRow + f * 1024 + (((ks << 5) + (kg << 3)) ^ (lm7 << 3));

  f32x4 acc[4][4];
  #pragma unroll
  for (int ii = 0; ii < 4; ++ii)
    #pragma unroll
    for (int jn = 0; jn < 4; ++jn)
      acc[ii][jn] = (f32x4){0.0f, 0.0f, 0.0f, 0.0f};

  auto STAGE = [&](int cc) {
    int slot = cc & 3;
    #pragma unroll
    for (int ii = 0; ii < 4; ++ii)
      gload16(aSrc + (size_t)ii * 8 * KTOT + cc * 64, &At[slot][(wid * 32 + ii * 8) * 64]);
  };

  short8 Bcur[8], Bnxt[8];
  STAGE(0);
  STAGE(1);
  #pragma unroll
  for (int nf = 0; nf < 4; ++nf)
    #pragma unroll
    for (int ks = 0; ks < 2; ++ks)
      Bcur[nf * 2 + ks] = *(const short8*)(bBase + nf * 16 * KTOT + 32 * ks);

  for (int c = 0; c < 6; ++c) {
    if (c + 2 < 6) STAGE(c + 2);
    if (c + 1 < 6) {
      const short* bb = bBase + (c + 1) * 64;
      #pragma unroll
      for (int nf = 0; nf < 4; ++nf)
        #pragma unroll
        for (int ks = 0; ks < 2; ++ks)
          Bnxt[nf * 2 + ks] = *(const short8*)(bb + nf * 16 * KTOT + 32 * ks);
    }
    if (c + 2 < 6)      asm volatile("s_waitcnt vmcnt(12) lgkmcnt(0)\n\ts_barrier" ::: "memory");
    else if (c + 1 < 6) asm volatile("s_waitcnt vmcnt(8) lgkmcnt(0)\n\ts_barrier" ::: "memory");
    else                asm volatile("s_waitcnt vmcnt(0) lgkmcnt(0)\n\ts_barrier" ::: "memory");

    const short* AtB = &At[c & 3][0];
    short8 Af[8];
    #pragma unroll
    for (int ii = 0; ii < 8; ++ii) Af[ii] = *(const short8*)(AtB + aof[ii]);
    __builtin_amdgcn_s_setprio(1);
    #pragma unroll
    for (int ks = 0; ks < 2; ++ks)
      #pragma unroll
      for (int mf = 0; mf < 4; ++mf)
        #pragma unroll
        for (int nf = 0; nf < 4; ++nf)
          acc[mf][nf] = __builtin_amdgcn_mfma_f32_16x16x32_bf16(Af[mf * 2 + ks], Bcur[nf * 2 + ks], acc[mf][nf], 0, 0, 0);
    __builtin_amdgcn_s_setprio(0);
    #pragma unroll
    for (int ii = 0; ii < 8; ++ii) Bcur[ii] = Bnxt[ii];
  }

  #pragma unroll
  for (int mf = 0; mf < 4; ++mf)
    #pragma unroll
    for (int nf = 0; nf < 4; ++nf) {
      int n = nt * 128 + wc * 64 + nf * 16 + lm;
      float bias = bh[n];
      #pragma unroll
      for (int j = 0; j < 4; ++j) {
        int R = R0 + wr * 64 + mf * 16 + kg * 4 + j;
        float v = acc[mf][nf][j] + bias;
        v = v > 0.0f ? v : 0.0f;
        out[(size_t)R * 256 + n] = v;
        if ((R & (S_LEN - 1)) == (S_LEN - 1))
          out[HN_OFF + (R >> 12) * 256 + n] = v;
      }
    }
}

extern "C" void kernel_launch(void* const* d_in, const int* in_sizes, int n_in,
                              void* d_out, int out_size, void* d_ws, size_t ws_size,
                              hipStream_t stream) {
  const float* x  = (const float*)d_in[0];
  const float* Wu = (const float*)d_in[1];
  const float* bu = (const float*)d_in[2];
  const float* Wh = (const float*)d_in[3];
  const float* bh = (const float*)d_in[4];
  const float* H  = (const float*)d_in[5];
  float* out = (float*)d_out;

  char* ws = (char*)d_ws;
  short* cp  = (short*)(ws + 131072);              // 557056 B
  short* Hb  = (short*)(ws + 688128);              // 2097152 B
  short* wht = (short*)(ws + 2785280);             // 196608 B
  short* mx  = (short*)(ws + 2981888);             // 25165824 B

  k_prep<<<12744, 256, 0, stream>>>(x, Wu, bu, H, Wh, mx, cp, Hb, wht);
  k_conv<<<512,  128, 0, stream>>>(cp, Hb, mx);
  k_gemm2<<<512, 256, 0, stream>>>(mx, wht, bh, out);
}

// Round 8
// 94.540 us; speedup vs baseline: 1.1865x; 1.1865x over previous
//
#include <hip/hip_runtime.h>

#define S_LEN 4096
#define B_SZ 8
#define KTOT 384            // M (256) + D (128)
#define CPROWS 544          // 8-elem rows per parity copy (zero-padded past 4096)
#define HN_OFF 8388608      // 8*4096*256

typedef __attribute__((ext_vector_type(8))) short short8;
typedef __attribute__((ext_vector_type(4))) float f32x4;

typedef const __attribute__((address_space(1))) unsigned int as1_u32;
typedef __attribute__((address_space(3))) unsigned int as3_u32;

__device__ __forceinline__ void gload16(const short* g, short* l) {
  __builtin_amdgcn_global_load_lds((as1_u32*)g, (as3_u32*)l, 16, 0, 0);
}

__device__ __forceinline__ short f2bf(float f) {
  union { float f; unsigned u; } v; v.f = f;
  unsigned r = v.u + 0x7FFFu + ((v.u >> 16) & 1u);
  return (short)(r >> 16);
}

// K1 fused prep (unchanged):
__global__ __launch_bounds__(256) void k_prep(const float* __restrict__ x,
                                              const float* __restrict__ Wu,
                                              const float* __restrict__ bu,
                                              const float* __restrict__ H,
                                              const float* __restrict__ Wh,
                                              short* __restrict__ mx,
                                              short* __restrict__ cp,
                                              short* __restrict__ Hb,
                                              short* __restrict__ wht) {
  int bx = blockIdx.x;
  if (bx >= 12360) {
    int j = (bx - 12360) * 256 + threadIdx.x;
    if (j < 256 * KTOT) {
      int n = j / KTOT, k = j % KTOT;
      wht[j] = f2bf(Wh[k * 256 + n]);
    }
    return;
  }
  if (bx >= 8264) {
    int i = (bx - 8264) * 256 + threadIdx.x;
    Hb[i] = f2bf(H[i]);
    return;
  }
  if (bx >= 8192) {
    int idx = (bx - 8192) * 256 + threadIdx.x;   // b(8)*p(8)*r(36)*j(8)
    if (idx < 18432) {
      int j = idx & 7;
      int r = 508 + ((idx >> 3) % 36);
      int rem = (idx >> 3) / 36;
      int p = rem & 7;
      int b = rem >> 3;
      int e = 8 * r + p + j;
      if (e >= S_LEN)
        cp[((size_t)(b * 8 + p) * CPROWS + r) * 8 + j] = 0;
    }
    return;
  }
  int row = bx * 4 + (threadIdx.x >> 6);   // b*4096 + t
  int l = threadIdx.x & 63;
  const float* xr = x + (size_t)row * 128;
  float x0 = xr[l], x1 = xr[l + 64];
  float s = x0 * Wu[l] + x1 * Wu[l + 64];
  #pragma unroll
  for (int m = 32; m >= 1; m >>= 1) s += __shfl_xor(s, m, 64);
  short* mrow = mx + (size_t)row * KTOT + 256;
  mrow[l]      = f2bf(x0);
  mrow[l + 64] = f2bf(x1);
  float v = s + bu[0];
  v = v > 0.0f ? v : 0.0f;
  short vb = f2bf(v);
  if (l < 8) {
    int t = row & (S_LEN - 1);
    int b = row >> 12;
    int e = (S_LEN - 1) - t;       // u_rev index of this element
    int p = l;
    if (e >= p) {
      int d = e - p;
      cp[((size_t)(b * 8 + p) * CPROWS + (d >> 3)) * 8 + (d & 7)] = vb;
    }
  }
}

// K2: Toeplitz GEMM. 512 blocks x 2 waves (128 thr). Block tile 128(s)x64(q),
// wave tile 64x64 (R6-verified addressing). In-block two-phase pairing
// (st=31-kk then st=kk) -> exactly 68 chunks/block, placement-proof balance.
// LDS ring-3 = 36KB -> 4 blocks/CU co-resident (8 waves/CU = 2/SIMD) in
// independent 2-wave gangs. Ring-3 stage-after-barrier, exact vmcnt(6)/0.
__global__ __launch_bounds__(128) void k_conv(const short* __restrict__ cp,
                                              const short* __restrict__ Hb,
                                              short* __restrict__ mx) {
  __shared__ __attribute__((aligned(16))) short Bt[3][64 * 64];   // 24 KB
  __shared__ __attribute__((aligned(16))) short Aw[3][2048];      // 12 KB

  int bx = blockIdx.x;            // 512 = kk(16) * qq(4) * b(8)
  int kk = bx >> 5;
  int qq = (bx >> 3) & 3;
  int b  = bx & 7;
  int q0 = qq << 6;

  int tid = threadIdx.x;
  int lane = tid & 63, wid = tid >> 6;   // 2 waves; wid = s-half
  int lm = lane & 15, kg = lane >> 4;
  int l3 = lane >> 3, l7 = lane & 7;
  int lm7 = lm & 7;

  // B staging: 64 q-rows/chunk; wave wid stages rows wid*32 + ii*8 + l3.
  // Source col pre-swizzled (l7^l3) -> linear LDS dest is XOR-swizzled by row.
  const short* bSrc = Hb + (size_t)(q0 + wid * 32 + l3) * S_LEN + ((l7 ^ l3) << 3);

  // A parity base: source parity pre-permuted (l7-l3)&7 -> rotation swizzle
  // on linear dest (R6-verified).
  const size_t aPar = (size_t)(b * 8 + ((l7 - l3) & 7)) * CPROWS * 8;

  // A-frag swizzled read offsets: u = dbase + adel; read at
  // sigma(u) = (u&~7)|((u+(u>>3))&7). Dedup: (0,1)->+32, (1,1)->+16.
  int dbase = 127 - 64 * wid - lm + 8 * kg;
  const int adel[6] = {0, -16, -32, -48, 32, 16};
  int aof[6];
  #pragma unroll
  for (int ii = 0; ii < 6; ++ii) {
    int u = dbase + adel[ii];
    aof[ii] = ((u & ~7) | ((u + (u >> 3)) & 7)) << 3;   // shorts
  }

  // B-frag offsets (rows 0..63 = q - q0)
  int bof[8];
  #pragma unroll
  for (int nf = 0; nf < 4; ++nf)
    #pragma unroll
    for (int ks = 0; ks < 2; ++ks)
      bof[nf * 2 + ks] = lm * 64 + nf * 1024 + (((ks << 5) + (kg << 3)) ^ (lm7 << 3));

  for (int ph = 0; ph < 2; ++ph) {
    int st = ph ? kk : (31 - kk);
    int s0 = st << 7;
    int asbase = 496 - 16 * st;
    const short* aSrc = cp + aPar + (size_t)(asbase + l3) * 8;
    int nchunks = 2 * st + 2;

    f32x4 acc[4][4];
    #pragma unroll
    for (int ii = 0; ii < 4; ++ii)
      #pragma unroll
      for (int jn = 0; jn < 4; ++jn)
        acc[ii][jn] = (f32x4){0.0f, 0.0f, 0.0f, 0.0f};

    auto STAGE = [&](int cc, int slot) {
      #pragma unroll
      for (int ii = 0; ii < 4; ++ii)
        gload16(bSrc + (size_t)ii * 8 * S_LEN + cc * 64, &Bt[slot][(wid * 32 + ii * 8) * 64]);
      #pragma unroll
      for (int ii = 0; ii < 2; ++ii)
        gload16(aSrc + (2 * wid + ii) * 64 + cc * 64, &Aw[slot][(2 * wid + ii) * 512]);
    };

    STAGE(0, 0);
    STAGE(1, 1);

    int cur = 0;                       // slot of chunk c
    for (int c = 0; c < nchunks; ++c) {
      if (c + 1 < nchunks) asm volatile("s_waitcnt vmcnt(6) lgkmcnt(0)\n\ts_barrier" ::: "memory");
      else                 asm volatile("s_waitcnt vmcnt(0) lgkmcnt(0)\n\ts_barrier" ::: "memory");
      if (c + 2 < nchunks) {
        int tg = (cur >= 1) ? (cur - 1) : 2;
        STAGE(c + 2, tg);
      }
      const short* AwB = &Aw[cur][0];
      const short* BtB = &Bt[cur][0];
      short8 A[6];
      #pragma unroll
      for (int ii = 0; ii < 6; ++ii) A[ii] = *(const short8*)(AwB + aof[ii]);
      short8 Bf[8];
      #pragma unroll
      for (int ii = 0; ii < 8; ++ii) Bf[ii] = *(const short8*)(BtB + bof[ii]);
      __builtin_amdgcn_s_setprio(1);
      #pragma unroll
      for (int nf = 0; nf < 4; ++nf) {
        acc[0][nf] = __builtin_amdgcn_mfma_f32_16x16x32_bf16(A[0], Bf[nf * 2], acc[0][nf], 0, 0, 0);
        acc[1][nf] = __builtin_amdgcn_mfma_f32_16x16x32_bf16(A[1], Bf[nf * 2], acc[1][nf], 0, 0, 0);
        acc[2][nf] = __builtin_amdgcn_mfma_f32_16x16x32_bf16(A[2], Bf[nf * 2], acc[2][nf], 0, 0, 0);
        acc[3][nf] = __builtin_amdgcn_mfma_f32_16x16x32_bf16(A[3], Bf[nf * 2], acc[3][nf], 0, 0, 0);
      }
      #pragma unroll
      for (int nf = 0; nf < 4; ++nf) {
        acc[0][nf] = __builtin_amdgcn_mfma_f32_16x16x32_bf16(A[4], Bf[nf * 2 + 1], acc[0][nf], 0, 0, 0);
        acc[1][nf] = __builtin_amdgcn_mfma_f32_16x16x32_bf16(A[5], Bf[nf * 2 + 1], acc[1][nf], 0, 0, 0);
        acc[2][nf] = __builtin_amdgcn_mfma_f32_16x16x32_bf16(A[0], Bf[nf * 2 + 1], acc[2][nf], 0, 0, 0);
        acc[3][nf] = __builtin_amdgcn_mfma_f32_16x16x32_bf16(A[1], Bf[nf * 2 + 1], acc[3][nf], 0, 0, 0);
      }
      __builtin_amdgcn_s_setprio(0);
      cur = (cur == 2) ? 0 : cur + 1;
    }

    // all waves done reading this phase's LDS before next phase's staging
    asm volatile("s_waitcnt lgkmcnt(0)\n\ts_barrier" ::: "memory");

    // C/D layout: col = lane&15, row = (lane>>4)*4 + reg
    #pragma unroll
    for (int mf = 0; mf < 4; ++mf)
      #pragma unroll
      for (int nf = 0; nf < 4; ++nf)
        #pragma unroll
        for (int j = 0; j < 4; ++j) {
          int s = s0 + wid * 64 + mf * 16 + kg * 4 + j;
          int q = q0 + nf * 16 + lm;
          mx[(size_t)(b * S_LEN + s) * KTOT + q] = f2bf(acc[mf][nf][j]);
        }
  }
}

// K3: h = relu(mx @ W_h + b_h); h_n extra write for s==4095 rows. (unchanged)
__global__ __launch_bounds__(256, 2) void k_gemm2(const short* __restrict__ mx,
                                                  const short* __restrict__ wht,
                                                  const float* __restrict__ bh,
                                                  float* __restrict__ out) {
  __shared__ __attribute__((aligned(16))) short At[4][128 * 64];  // 64 KB

  int idx = blockIdx.x;       // 512 = 256 row-tiles * 2 n-tiles
  int nt = idx & 1;
  int rt = idx >> 1;
  int R0 = rt << 7;

  int tid = threadIdx.x;
  int lane = tid & 63, wid = tid >> 6;
  int wr = wid >> 1, wc = wid & 1;
  int lm = lane & 15, kg = lane >> 4;
  int l3 = lane >> 3, l7 = lane & 7;
  int lm7 = lm & 7;

  const short* aSrc  = mx  + (size_t)(R0 + wid * 32 + l3) * KTOT + ((l7 ^ l3) << 3);
  const short* bBase = wht + (size_t)(nt * 128 + wc * 64 + lm) * KTOT + 8 * kg;

  int aRow = (wr * 64 + lm) * 64;
  int aof[8];
  #pragma unroll
  for (int f = 0; f < 4; ++f)
    #pragma unroll
    for (int ks = 0; ks < 2; ++ks)
      aof[f * 2 + ks] = aRow + f * 1024 + (((ks << 5) + (kg << 3)) ^ (lm7 << 3));

  f32x4 acc[4][4];
  #pragma unroll
  for (int ii = 0; ii < 4; ++ii)
    #pragma unroll
    for (int jn = 0; jn < 4; ++jn)
      acc[ii][jn] = (f32x4){0.0f, 0.0f, 0.0f, 0.0f};

  auto STAGE = [&](int cc) {
    int slot = cc & 3;
    #pragma unroll
    for (int ii = 0; ii < 4; ++ii)
      gload16(aSrc + (size_t)ii * 8 * KTOT + cc * 64, &At[slot][(wid * 32 + ii * 8) * 64]);
  };

  short8 Bcur[8], Bnxt[8];
  STAGE(0);
  STAGE(1);
  #pragma unroll
  for (int nf = 0; nf < 4; ++nf)
    #pragma unroll
    for (int ks = 0; ks < 2; ++ks)
      Bcur[nf * 2 + ks] = *(const short8*)(bBase + nf * 16 * KTOT + 32 * ks);

  for (int c = 0; c < 6; ++c) {
    if (c + 2 < 6) STAGE(c + 2);
    if (c + 1 < 6) {
      const short* bb = bBase + (c + 1) * 64;
      #pragma unroll
      for (int nf = 0; nf < 4; ++nf)
        #pragma unroll
        for (int ks = 0; ks < 2; ++ks)
          Bnxt[nf * 2 + ks] = *(const short8*)(bb + nf * 16 * KTOT + 32 * ks);
    }
    if (c + 2 < 6)      asm volatile("s_waitcnt vmcnt(12) lgkmcnt(0)\n\ts_barrier" ::: "memory");
    else if (c + 1 < 6) asm volatile("s_waitcnt vmcnt(8) lgkmcnt(0)\n\ts_barrier" ::: "memory");
    else                asm volatile("s_waitcnt vmcnt(0) lgkmcnt(0)\n\ts_barrier" ::: "memory");

    const short* AtB = &At[c & 3][0];
    short8 Af[8];
    #pragma unroll
    for (int ii = 0; ii < 8; ++ii) Af[ii] = *(const short8*)(AtB + aof[ii]);
    __builtin_amdgcn_s_setprio(1);
    #pragma unroll
    for (int ks = 0; ks < 2; ++ks)
      #pragma unroll
      for (int mf = 0; mf < 4; ++mf)
        #pragma unroll
        for (int nf = 0; nf < 4; ++nf)
          acc[mf][nf] = __builtin_amdgcn_mfma_f32_16x16x32_bf16(Af[mf * 2 + ks], Bcur[nf * 2 + ks], acc[mf][nf], 0, 0, 0);
    __builtin_amdgcn_s_setprio(0);
    #pragma unroll
    for (int ii = 0; ii < 8; ++ii) Bcur[ii] = Bnxt[ii];
  }

  #pragma unroll
  for (int mf = 0; mf < 4; ++mf)
    #pragma unroll
    for (int nf = 0; nf < 4; ++nf) {
      int n = nt * 128 + wc * 64 + nf * 16 + lm;
      float bias = bh[n];
      #pragma unroll
      for (int j = 0; j < 4; ++j) {
        int R = R0 + wr * 64 + mf * 16 + kg * 4 + j;
        float v = acc[mf][nf][j] + bias;
        v = v > 0.0f ? v : 0.0f;
        out[(size_t)R * 256 + n] = v;
        if ((R & (S_LEN - 1)) == (S_LEN - 1))
          out[HN_OFF + (R >> 12) * 256 + n] = v;
      }
    }
}

extern "C" void kernel_launch(void* const* d_in, const int* in_sizes, int n_in,
                              void* d_out, int out_size, void* d_ws, size_t ws_size,
                              hipStream_t stream) {
  const float* x  = (const float*)d_in[0];
  const float* Wu = (const float*)d_in[1];
  const float* bu = (const float*)d_in[2];
  const float* Wh = (const float*)d_in[3];
  const float* bh = (const float*)d_in[4];
  const float* H  = (const float*)d_in[5];
  float* out = (float*)d_out;

  char* ws = (char*)d_ws;
  short* cp  = (short*)(ws + 131072);              // 557056 B
  short* Hb  = (short*)(ws + 688128);              // 2097152 B
  short* wht = (short*)(ws + 2785280);             // 196608 B
  short* mx  = (short*)(ws + 2981888);             // 25165824 B

  k_prep<<<12744, 256, 0, stream>>>(x, Wu, bu, H, Wh, mx, cp, Hb, wht);
  k_conv<<<512,  128, 0, stream>>>(cp, Hb, mx);
  k_gemm2<<<512, 256, 0, stream>>>(mx, wht, bh, out);
}

// Round 9
// 93.916 us; speedup vs baseline: 1.1944x; 1.0066x over previous
//
#include <hip/hip_runtime.h>

#define S_LEN 4096
#define B_SZ 8
#define KTOT 384            // M (256) + D (128)
#define CPROWS 544          // 8-elem rows per parity copy (zero-padded past 4096)
#define HN_OFF 8388608      // 8*4096*256

typedef __attribute__((ext_vector_type(8))) short short8;
typedef __attribute__((ext_vector_type(4))) float f32x4;

typedef const __attribute__((address_space(1))) unsigned int as1_u32;
typedef __attribute__((address_space(3))) unsigned int as3_u32;

__device__ __forceinline__ void gload16(const short* g, short* l) {
  __builtin_amdgcn_global_load_lds((as1_u32*)g, (as3_u32*)l, 16, 0, 0);
}

__device__ __forceinline__ short f2bf(float f) {
  union { float f; unsigned u; } v; v.f = f;
  unsigned r = v.u + 0x7FFFu + ((v.u >> 16) & 1u);
  return (short)(r >> 16);
}

// K1 fused prep (unchanged):
__global__ __launch_bounds__(256) void k_prep(const float* __restrict__ x,
                                              const float* __restrict__ Wu,
                                              const float* __restrict__ bu,
                                              const float* __restrict__ H,
                                              const float* __restrict__ Wh,
                                              short* __restrict__ mx,
                                              short* __restrict__ cp,
                                              short* __restrict__ Hb,
                                              short* __restrict__ wht) {
  int bx = blockIdx.x;
  if (bx >= 12360) {
    int j = (bx - 12360) * 256 + threadIdx.x;
    if (j < 256 * KTOT) {
      int n = j / KTOT, k = j % KTOT;
      wht[j] = f2bf(Wh[k * 256 + n]);
    }
    return;
  }
  if (bx >= 8264) {
    int i = (bx - 8264) * 256 + threadIdx.x;
    Hb[i] = f2bf(H[i]);
    return;
  }
  if (bx >= 8192) {
    int idx = (bx - 8192) * 256 + threadIdx.x;   // b(8)*p(8)*r(36)*j(8)
    if (idx < 18432) {
      int j = idx & 7;
      int r = 508 + ((idx >> 3) % 36);
      int rem = (idx >> 3) / 36;
      int p = rem & 7;
      int b = rem >> 3;
      int e = 8 * r + p + j;
      if (e >= S_LEN)
        cp[((size_t)(b * 8 + p) * CPROWS + r) * 8 + j] = 0;
    }
    return;
  }
  int row = bx * 4 + (threadIdx.x >> 6);   // b*4096 + t
  int l = threadIdx.x & 63;
  const float* xr = x + (size_t)row * 128;
  float x0 = xr[l], x1 = xr[l + 64];
  float s = x0 * Wu[l] + x1 * Wu[l + 64];
  #pragma unroll
  for (int m = 32; m >= 1; m >>= 1) s += __shfl_xor(s, m, 64);
  short* mrow = mx + (size_t)row * KTOT + 256;
  mrow[l]      = f2bf(x0);
  mrow[l + 64] = f2bf(x1);
  float v = s + bu[0];
  v = v > 0.0f ? v : 0.0f;
  short vb = f2bf(v);
  if (l < 8) {
    int t = row & (S_LEN - 1);
    int b = row >> 12;
    int e = (S_LEN - 1) - t;       // u_rev index of this element
    int p = l;
    if (e >= p) {
      int d = e - p;
      cp[((size_t)(b * 8 + p) * CPROWS + (d >> 3)) * 8 + (d & 7)] = vb;
    }
  }
}

// K2: Toeplitz GEMM, m[b][s][q] = sum_tau u[b][s-tau]*H[q][tau].
// 512 blocks x 4 waves, 128x128 tile, wave tile 64x64 (R3/R6-verified algebra).
// Ring-3 LDS = 60 KB (B 48 + A 12) -> 2 blocks/CU = 2 waves/SIMD.
// Stage-after-barrier ring-3 (R8-proven race-free), exact vmcnt(5)/0.
// Packing-robust balance map: every plausible co-resident block pair
// ((2j,2j+1), (i,i+256), misaligned stride-1) has st-sum ~31 -> ~66 chunks.
__global__ __launch_bounds__(256) void k_conv(const short* __restrict__ cp,
                                              const short* __restrict__ Hb,
                                              short* __restrict__ mx) {
  __shared__ __attribute__((aligned(16))) short Bt[3][128 * 64];  // 48 KB
  __shared__ __attribute__((aligned(16))) short Aw[3][2048];      // 12 KB

  int i = blockIdx.x;                 // 512 blocks
  int j  = i >> 1, lo = i & 1;
  int jj = j & 127;
  int fj = (j >> 7) ? (31 - (jj >> 3)) : (jj >> 3);
  int st = lo ? (31 - fj) : fj;
  int qt = lo;
  int b  = j & 7;
  int s0 = st << 7, q0 = qt << 7;

  int tid = threadIdx.x;
  int lane = tid & 63, wid = tid >> 6;
  int wr = wid >> 1, wc = wid & 1;      // wave tile 64(s) x 64(q)
  int lm = lane & 15, kg = lane >> 4;
  int l3 = lane >> 3, l7 = lane & 7;
  int lm7 = lm & 7;

  // B staging (XOR swizzle via pre-swizzled source col; linear LDS dest)
  const short* bSrc = Hb + (size_t)(q0 + wid * 32 + l3) * S_LEN + ((l7 ^ l3) << 3);

  // A staging: parity pre-permuted (l7-l3)&7 -> rotation swizzle on linear dest
  int asbase = 496 - 16 * st;
  const size_t aPar = (size_t)(b * 8 + ((l7 - l3) & 7)) * CPROWS * 8;
  const short* aSrc = cp + aPar + (size_t)(asbase + wid * 8 + l3) * 8;

  // A-frag swizzled read offsets: u = dbase + adel; sigma(u)=(u&~7)|((u+(u>>3))&7)
  int dbase = 127 - 64 * wr - lm + 8 * kg;
  const int adel[6] = {0, -16, -32, -48, 32, 16};  // (mf,ks): i<4->(i,0); 4->(0,1); 5->(1,1)
  int aof[6];
  #pragma unroll
  for (int ii = 0; ii < 6; ++ii) {
    int u = dbase + adel[ii];
    aof[ii] = ((u & ~7) | ((u + (u >> 3)) & 7)) << 3;   // shorts
  }

  // B-fragment LDS offsets
  int bRow = (wc * 64 + lm) * 64;
  int bof[8];
  #pragma unroll
  for (int nf = 0; nf < 4; ++nf)
    #pragma unroll
    for (int ks = 0; ks < 2; ++ks)
      bof[nf * 2 + ks] = bRow + nf * 1024 + (((ks << 5) + (kg << 3)) ^ (lm7 << 3));

  f32x4 acc[4][4];
  #pragma unroll
  for (int ii = 0; ii < 4; ++ii)
    #pragma unroll
    for (int jn = 0; jn < 4; ++jn)
      acc[ii][jn] = (f32x4){0.0f, 0.0f, 0.0f, 0.0f};

  int nchunks = 2 * st + 2;

  auto STAGE = [&](int cc, int slot) {
    #pragma unroll
    for (int ii = 0; ii < 4; ++ii)
      gload16(bSrc + (size_t)ii * 8 * S_LEN + cc * 64, &Bt[slot][(wid * 32 + ii * 8) * 64]);
    gload16(aSrc + cc * 64, &Aw[slot][wid * 512]);
  };

  STAGE(0, 0);
  STAGE(1, 1);

  int cur = 0;                       // slot of chunk c
  for (int c = 0; c < nchunks; ++c) {
    if (c + 1 < nchunks) asm volatile("s_waitcnt vmcnt(5) lgkmcnt(0)\n\ts_barrier" ::: "memory");
    else                 asm volatile("s_waitcnt vmcnt(0) lgkmcnt(0)\n\ts_barrier" ::: "memory");
    if (c + 2 < nchunks) {
      int tg = (cur >= 1) ? (cur - 1) : 2;
      STAGE(c + 2, tg);
    }
    const short* AwB = &Aw[cur][0];
    const short* BtB = &Bt[cur][0];
    short8 A[6];
    #pragma unroll
    for (int ii = 0; ii < 6; ++ii) A[ii] = *(const short8*)(AwB + aof[ii]);
    short8 Bf[8];
    #pragma unroll
    for (int ii = 0; ii < 8; ++ii) Bf[ii] = *(const short8*)(BtB + bof[ii]);
    __builtin_amdgcn_s_setprio(1);
    #pragma unroll
    for (int nf = 0; nf < 4; ++nf) {
      acc[0][nf] = __builtin_amdgcn_mfma_f32_16x16x32_bf16(A[0], Bf[nf * 2], acc[0][nf], 0, 0, 0);
      acc[1][nf] = __builtin_amdgcn_mfma_f32_16x16x32_bf16(A[1], Bf[nf * 2], acc[1][nf], 0, 0, 0);
      acc[2][nf] = __builtin_amdgcn_mfma_f32_16x16x32_bf16(A[2], Bf[nf * 2], acc[2][nf], 0, 0, 0);
      acc[3][nf] = __builtin_amdgcn_mfma_f32_16x16x32_bf16(A[3], Bf[nf * 2], acc[3][nf], 0, 0, 0);
    }
    #pragma unroll
    for (int nf = 0; nf < 4; ++nf) {
      acc[0][nf] = __builtin_amdgcn_mfma_f32_16x16x32_bf16(A[4], Bf[nf * 2 + 1], acc[0][nf], 0, 0, 0);
      acc[1][nf] = __builtin_amdgcn_mfma_f32_16x16x32_bf16(A[5], Bf[nf * 2 + 1], acc[1][nf], 0, 0, 0);
      acc[2][nf] = __builtin_amdgcn_mfma_f32_16x16x32_bf16(A[0], Bf[nf * 2 + 1], acc[2][nf], 0, 0, 0);
      acc[3][nf] = __builtin_amdgcn_mfma_f32_16x16x32_bf16(A[1], Bf[nf * 2 + 1], acc[3][nf], 0, 0, 0);
    }
    __builtin_amdgcn_s_setprio(0);
    cur = (cur == 2) ? 0 : cur + 1;
  }

  // C/D layout: col = lane&15, row = (lane>>4)*4 + reg
  #pragma unroll
  for (int mf = 0; mf < 4; ++mf)
    #pragma unroll
    for (int nf = 0; nf < 4; ++nf)
      #pragma unroll
      for (int j2 = 0; j2 < 4; ++j2) {
        int s = s0 + wr * 64 + mf * 16 + kg * 4 + j2;
        int q = q0 + wc * 64 + nf * 16 + lm;
        mx[(size_t)(b * S_LEN + s) * KTOT + q] = f2bf(acc[mf][nf][j2]);
      }
}

// K3: h = relu(mx @ W_h + b_h); h_n extra write for s==4095 rows. (unchanged)
__global__ __launch_bounds__(256, 2) void k_gemm2(const short* __restrict__ mx,
                                                  const short* __restrict__ wht,
                                                  const float* __restrict__ bh,
                                                  float* __restrict__ out) {
  __shared__ __attribute__((aligned(16))) short At[4][128 * 64];  // 64 KB

  int idx = blockIdx.x;       // 512 = 256 row-tiles * 2 n-tiles
  int nt = idx & 1;
  int rt = idx >> 1;
  int R0 = rt << 7;

  int tid = threadIdx.x;
  int lane = tid & 63, wid = tid >> 6;
  int wr = wid >> 1, wc = wid & 1;
  int lm = lane & 15, kg = lane >> 4;
  int l3 = lane >> 3, l7 = lane & 7;
  int lm7 = lm & 7;

  const short* aSrc  = mx  + (size_t)(R0 + wid * 32 + l3) * KTOT + ((l7 ^ l3) << 3);
  const short* bBase = wht + (size_t)(nt * 128 + wc * 64 + lm) * KTOT + 8 * kg;

  int aRow = (wr * 64 + lm) * 64;
  int aof[8];
  #pragma unroll
  for (int f = 0; f < 4; ++f)
    #pragma unroll
    for (int ks = 0; ks < 2; ++ks)
      aof[f * 2 + ks] = aRow + f * 1024 + (((ks << 5) + (kg << 3)) ^ (lm7 << 3));

  f32x4 acc[4][4];
  #pragma unroll
  for (int ii = 0; ii < 4; ++ii)
    #pragma unroll
    for (int jn = 0; jn < 4; ++jn)
      acc[ii][jn] = (f32x4){0.0f, 0.0f, 0.0f, 0.0f};

  auto STAGE = [&](int cc) {
    int slot = cc & 3;
    #pragma unroll
    for (int ii = 0; ii < 4; ++ii)
      gload16(aSrc + (size_t)ii * 8 * KTOT + cc * 64, &At[slot][(wid * 32 + ii * 8) * 64]);
  };

  short8 Bcur[8], Bnxt[8];
  STAGE(0);
  STAGE(1);
  #pragma unroll
  for (int nf = 0; nf < 4; ++nf)
    #pragma unroll
    for (int ks = 0; ks < 2; ++ks)
      Bcur[nf * 2 + ks] = *(const short8*)(bBase + nf * 16 * KTOT + 32 * ks);

  for (int c = 0; c < 6; ++c) {
    if (c + 2 < 6) STAGE(c + 2);
    if (c + 1 < 6) {
      const short* bb = bBase + (c + 1) * 64;
      #pragma unroll
      for (int nf = 0; nf < 4; ++nf)
        #pragma unroll
        for (int ks = 0; ks < 2; ++ks)
          Bnxt[nf * 2 + ks] = *(const short8*)(bb + nf * 16 * KTOT + 32 * ks);
    }
    if (c + 2 < 6)      asm volatile("s_waitcnt vmcnt(12) lgkmcnt(0)\n\ts_barrier" ::: "memory");
    else if (c + 1 < 6) asm volatile("s_waitcnt vmcnt(8) lgkmcnt(0)\n\ts_barrier" ::: "memory");
    else                asm volatile("s_waitcnt vmcnt(0) lgkmcnt(0)\n\ts_barrier" ::: "memory");

    const short* AtB = &At[c & 3][0];
    short8 Af[8];
    #pragma unroll
    for (int ii = 0; ii < 8; ++ii) Af[ii] = *(const short8*)(AtB + aof[ii]);
    __builtin_amdgcn_s_setprio(1);
    #pragma unroll
    for (int ks = 0; ks < 2; ++ks)
      #pragma unroll
      for (int mf = 0; mf < 4; ++mf)
        #pragma unroll
        for (int nf = 0; nf < 4; ++nf)
          acc[mf][nf] = __builtin_amdgcn_mfma_f32_16x16x32_bf16(Af[mf * 2 + ks], Bcur[nf * 2 + ks], acc[mf][nf], 0, 0, 0);
    __builtin_amdgcn_s_setprio(0);
    #pragma unroll
    for (int ii = 0; ii < 8; ++ii) Bcur[ii] = Bnxt[ii];
  }

  #pragma unroll
  for (int mf = 0; mf < 4; ++mf)
    #pragma unroll
    for (int nf = 0; nf < 4; ++nf) {
      int n = nt * 128 + wc * 64 + nf * 16 + lm;
      float bias = bh[n];
      #pragma unroll
      for (int j = 0; j < 4; ++j) {
        int R = R0 + wr * 64 + mf * 16 + kg * 4 + j;
        float v = acc[mf][nf][j] + bias;
        v = v > 0.0f ? v : 0.0f;
        out[(size_t)R * 256 + n] = v;
        if ((R & (S_LEN - 1)) == (S_LEN - 1))
          out[HN_OFF + (R >> 12) * 256 + n] = v;
      }
    }
}

extern "C" void kernel_launch(void* const* d_in, const int* in_sizes, int n_in,
                              void* d_out, int out_size, void* d_ws, size_t ws_size,
                              hipStream_t stream) {
  const float* x  = (const float*)d_in[0];
  const float* Wu = (const float*)d_in[1];
  const float* bu = (const float*)d_in[2];
  const float* Wh = (const float*)d_in[3];
  const float* bh = (const float*)d_in[4];
  const float* H  = (const float*)d_in[5];
  float* out = (float*)d_out;

  char* ws = (char*)d_ws;
  short* cp  = (short*)(ws + 131072);              // 557056 B
  short* Hb  = (short*)(ws + 688128);              // 2097152 B
  short* wht = (short*)(ws + 2785280);             // 196608 B
  short* mx  = (short*)(ws + 2981888);             // 25165824 B

  k_prep<<<12744, 256, 0, stream>>>(x, Wu, bu, H, Wh, mx, cp, Hb, wht);
  k_conv<<<512,  256, 0, stream>>>(cp, Hb, mx);
  k_gemm2<<<512, 256, 0, stream>>>(mx, wht, bh, out);
}

// Round 10
// 81.934 us; speedup vs baseline: 1.3691x; 1.1462x over previous
//
#include <hip/hip_runtime.h>

#define S_LEN 4096
#define B_SZ 8
#define KTOT 384            // M (256) + D (128)
#define CPROWS 544          // 8-elem rows per parity copy (zero-padded past 4096)
#define HN_OFF 8388608      // 8*4096*256

typedef __attribute__((ext_vector_type(8))) short short8;
typedef __attribute__((ext_vector_type(4))) float f32x4;

typedef const __attribute__((address_space(1))) unsigned int as1_u32;
typedef __attribute__((address_space(3))) unsigned int as3_u32;

__device__ __forceinline__ void gload16(const short* g, short* l) {
  __builtin_amdgcn_global_load_lds((as1_u32*)g, (as3_u32*)l, 16, 0, 0);
}

__device__ __forceinline__ short f2bf(float f) {
  union { float f; unsigned u; } v; v.f = f;
  unsigned r = v.u + 0x7FFFu + ((v.u >> 16) & 1u);
  return (short)(r >> 16);
}

// K1 fused prep (unchanged):
__global__ __launch_bounds__(256) void k_prep(const float* __restrict__ x,
                                              const float* __restrict__ Wu,
                                              const float* __restrict__ bu,
                                              const float* __restrict__ H,
                                              const float* __restrict__ Wh,
                                              short* __restrict__ mx,
                                              short* __restrict__ cp,
                                              short* __restrict__ Hb,
                                              short* __restrict__ wht) {
  int bx = blockIdx.x;
  if (bx >= 12360) {
    int j = (bx - 12360) * 256 + threadIdx.x;
    if (j < 256 * KTOT) {
      int n = j / KTOT, k = j % KTOT;
      wht[j] = f2bf(Wh[k * 256 + n]);
    }
    return;
  }
  if (bx >= 8264) {
    int i = (bx - 8264) * 256 + threadIdx.x;
    Hb[i] = f2bf(H[i]);
    return;
  }
  if (bx >= 8192) {
    int idx = (bx - 8192) * 256 + threadIdx.x;   // b(8)*p(8)*r(36)*j(8)
    if (idx < 18432) {
      int j = idx & 7;
      int r = 508 + ((idx >> 3) % 36);
      int rem = (idx >> 3) / 36;
      int p = rem & 7;
      int b = rem >> 3;
      int e = 8 * r + p + j;
      if (e >= S_LEN)
        cp[((size_t)(b * 8 + p) * CPROWS + r) * 8 + j] = 0;
    }
    return;
  }
  int row = bx * 4 + (threadIdx.x >> 6);   // b*4096 + t
  int l = threadIdx.x & 63;
  const float* xr = x + (size_t)row * 128;
  float x0 = xr[l], x1 = xr[l + 64];
  float s = x0 * Wu[l] + x1 * Wu[l + 64];
  #pragma unroll
  for (int m = 32; m >= 1; m >>= 1) s += __shfl_xor(s, m, 64);
  short* mrow = mx + (size_t)row * KTOT + 256;
  mrow[l]      = f2bf(x0);
  mrow[l + 64] = f2bf(x1);
  float v = s + bu[0];
  v = v > 0.0f ? v : 0.0f;
  short vb = f2bf(v);
  if (l < 8) {
    int t = row & (S_LEN - 1);
    int b = row >> 12;
    int e = (S_LEN - 1) - t;       // u_rev index of this element
    int p = l;
    if (e >= p) {
      int d = e - p;
      cp[((size_t)(b * 8 + p) * CPROWS + (d >> 3)) * 8 + (d & 7)] = vb;
    }
  }
}

// K2: Toeplitz GEMM — Round-3 structure (best measured per-chunk time:
// ring-4 80KB = exact 2 blocks/CU, STAGE-before-wait 2-deep, vmcnt(10/5/0),
// XOR-A swizzle) + Round-9 packing-robust balance map (co-resident pair
// chunk-sum == 66 under (2j,2j+1), (i,i+256), and stride-1 pairings).
__global__ __launch_bounds__(256) void k_conv(const short* __restrict__ cp,
                                              const short* __restrict__ Hb,
                                              short* __restrict__ mx) {
  __shared__ __attribute__((aligned(16))) short Bt[4][128 * 64];  // 64 KB
  __shared__ __attribute__((aligned(16))) short Aw[4][2048];      // 16 KB

  int i = blockIdx.x;                 // 512 blocks, balance map
  int j  = i >> 1, lo = i & 1;
  int jj = j & 127;
  int fj = (j >> 7) ? (31 - (jj >> 3)) : (jj >> 3);
  int st = lo ? (31 - fj) : fj;
  int qt = lo;
  int b  = j & 7;
  int s0 = st << 7, q0 = qt << 7;

  int tid = threadIdx.x;
  int lane = tid & 63, wid = tid >> 6;
  int wr = wid >> 1, wc = wid & 1;      // wave tile 64(s) x 64(q)
  int lm = lane & 15, kg = lane >> 4;
  int l3 = lane >> 3, l7 = lane & 7;
  int lm7 = lm & 7;

  int asbase = 496 - 16 * st;
  // staging sources (advance 64 shorts per chunk); both LDS layouts are
  // XOR-swizzled via pre-swizzled source (l7^l3), LDS dest stays linear.
  const short* bSrc = Hb + (size_t)(q0 + wid * 32 + l3) * S_LEN + ((l7 ^ l3) << 3);
  const short* aSrc = cp + ((size_t)(b * 8 + (l7 ^ l3)) * CPROWS + asbase + wid * 8 + l3) * 8;

  // A-frag offsets: data unit delta = dbase + adel; read at swizzled
  // unit (d&~7)|((d&7)^((d>>3)&7)). Dedup: (ks1,mf2)=(ks0,mf0),(ks1,mf3)=(ks0,mf1).
  int dbase = 127 - 64 * wr - lm + 8 * kg;
  int aof[6];
  #pragma unroll
  for (int ii = 0; ii < 6; ++ii) {
    int d = (ii < 4) ? (dbase - 16 * ii) : (dbase + 96 - 16 * ii);  // ii=4:+32, ii=5:+16
    aof[ii] = ((d & ~7) | ((d & 7) ^ ((d >> 3) & 7))) << 3;         // shorts
  }
  int bRow = (wc * 64 + lm) * 64;
  int bof[8];
  #pragma unroll
  for (int nf = 0; nf < 4; ++nf)
    #pragma unroll
    for (int ks = 0; ks < 2; ++ks)
      bof[nf * 2 + ks] = bRow + nf * 1024 + (((ks << 5) + (kg << 3)) ^ (lm7 << 3));

  f32x4 acc[4][4];
  #pragma unroll
  for (int ii = 0; ii < 4; ++ii)
    #pragma unroll
    for (int jn = 0; jn < 4; ++jn)
      acc[ii][jn] = (f32x4){0.0f, 0.0f, 0.0f, 0.0f};

  int nchunks = 2 * st + 2;

  auto STAGE = [&](int cc) {
    int slot = cc & 3;
    #pragma unroll
    for (int ii = 0; ii < 4; ++ii)
      gload16(bSrc + (size_t)ii * 8 * S_LEN + cc * 64, &Bt[slot][(wid * 32 + ii * 8) * 64]);
    gload16(aSrc + cc * 64, &Aw[slot][wid * 512]);
  };

  STAGE(0);
  STAGE(1);

  for (int c = 0; c < nchunks; ++c) {
    if (c + 2 < nchunks) {
      STAGE(c + 2);
      asm volatile("s_waitcnt vmcnt(10) lgkmcnt(0)\n\ts_barrier" ::: "memory");
    } else if (c + 1 < nchunks) {
      asm volatile("s_waitcnt vmcnt(5) lgkmcnt(0)\n\ts_barrier" ::: "memory");
    } else {
      asm volatile("s_waitcnt vmcnt(0) lgkmcnt(0)\n\ts_barrier" ::: "memory");
    }
    const short* AwB = &Aw[c & 3][0];
    const short* BtB = &Bt[c & 3][0];
    short8 A[6];
    #pragma unroll
    for (int ii = 0; ii < 6; ++ii) A[ii] = *(const short8*)(AwB + aof[ii]);
    short8 Bf[8];
    #pragma unroll
    for (int ii = 0; ii < 8; ++ii) Bf[ii] = *(const short8*)(BtB + bof[ii]);
    __builtin_amdgcn_s_setprio(1);
    #pragma unroll
    for (int nf = 0; nf < 4; ++nf) {
      acc[0][nf] = __builtin_amdgcn_mfma_f32_16x16x32_bf16(A[0], Bf[nf * 2], acc[0][nf], 0, 0, 0);
      acc[1][nf] = __builtin_amdgcn_mfma_f32_16x16x32_bf16(A[1], Bf[nf * 2], acc[1][nf], 0, 0, 0);
      acc[2][nf] = __builtin_amdgcn_mfma_f32_16x16x32_bf16(A[2], Bf[nf * 2], acc[2][nf], 0, 0, 0);
      acc[3][nf] = __builtin_amdgcn_mfma_f32_16x16x32_bf16(A[3], Bf[nf * 2], acc[3][nf], 0, 0, 0);
    }
    #pragma unroll
    for (int nf = 0; nf < 4; ++nf) {
      acc[0][nf] = __builtin_amdgcn_mfma_f32_16x16x32_bf16(A[4], Bf[nf * 2 + 1], acc[0][nf], 0, 0, 0);
      acc[1][nf] = __builtin_amdgcn_mfma_f32_16x16x32_bf16(A[5], Bf[nf * 2 + 1], acc[1][nf], 0, 0, 0);
      acc[2][nf] = __builtin_amdgcn_mfma_f32_16x16x32_bf16(A[0], Bf[nf * 2 + 1], acc[2][nf], 0, 0, 0);
      acc[3][nf] = __builtin_amdgcn_mfma_f32_16x16x32_bf16(A[1], Bf[nf * 2 + 1], acc[3][nf], 0, 0, 0);
    }
    __builtin_amdgcn_s_setprio(0);
  }

  // C/D layout: col = lane&15, row = (lane>>4)*4 + reg
  #pragma unroll
  for (int mf = 0; mf < 4; ++mf)
    #pragma unroll
    for (int nf = 0; nf < 4; ++nf)
      #pragma unroll
      for (int j2 = 0; j2 < 4; ++j2) {
        int s = s0 + wr * 64 + mf * 16 + kg * 4 + j2;
        int q = q0 + wc * 64 + nf * 16 + lm;
        mx[(size_t)(b * S_LEN + s) * KTOT + q] = f2bf(acc[mf][nf][j2]);
      }
}

// K3: h = relu(mx @ W_h + b_h); h_n extra write for s==4095 rows. (unchanged)
__global__ __launch_bounds__(256, 2) void k_gemm2(const short* __restrict__ mx,
                                                  const short* __restrict__ wht,
                                                  const float* __restrict__ bh,
                                                  float* __restrict__ out) {
  __shared__ __attribute__((aligned(16))) short At[4][128 * 64];  // 64 KB

  int idx = blockIdx.x;       // 512 = 256 row-tiles * 2 n-tiles
  int nt = idx & 1;
  int rt = idx >> 1;
  int R0 = rt << 7;

  int tid = threadIdx.x;
  int lane = tid & 63, wid = tid >> 6;
  int wr = wid >> 1, wc = wid & 1;
  int lm = lane & 15, kg = lane >> 4;
  int l3 = lane >> 3, l7 = lane & 7;
  int lm7 = lm & 7;

  const short* aSrc  = mx  + (size_t)(R0 + wid * 32 + l3) * KTOT + ((l7 ^ l3) << 3);
  const short* bBase = wht + (size_t)(nt * 128 + wc * 64 + lm) * KTOT + 8 * kg;

  int aRow = (wr * 64 + lm) * 64;
  int aof[8];
  #pragma unroll
  for (int f = 0; f < 4; ++f)
    #pragma unroll
    for (int ks = 0; ks < 2; ++ks)
      aof[f * 2 + ks] = aRow + f * 1024 + (((ks << 5) + (kg << 3)) ^ (lm7 << 3));

  f32x4 acc[4][4];
  #pragma unroll
  for (int ii = 0; ii < 4; ++ii)
    #pragma unroll
    for (int jn = 0; jn < 4; ++jn)
      acc[ii][jn] = (f32x4){0.0f, 0.0f, 0.0f, 0.0f};

  auto STAGE = [&](int cc) {
    int slot = cc & 3;
    #pragma unroll
    for (int ii = 0; ii < 4; ++ii)
      gload16(aSrc + (size_t)ii * 8 * KTOT + cc * 64, &At[slot][(wid * 32 + ii * 8) * 64]);
  };

  short8 Bcur[8], Bnxt[8];
  STAGE(0);
  STAGE(1);
  #pragma unroll
  for (int nf = 0; nf < 4; ++nf)
    #pragma unroll
    for (int ks = 0; ks < 2; ++ks)
      Bcur[nf * 2 + ks] = *(const short8*)(bBase + nf * 16 * KTOT + 32 * ks);

  for (int c = 0; c < 6; ++c) {
    if (c + 2 < 6) STAGE(c + 2);
    if (c + 1 < 6) {
      const short* bb = bBase + (c + 1) * 64;
      #pragma unroll
      for (int nf = 0; nf < 4; ++nf)
        #pragma unroll
        for (int ks = 0; ks < 2; ++ks)
          Bnxt[nf * 2 + ks] = *(const short8*)(bb + nf * 16 * KTOT + 32 * ks);
    }
    if (c + 2 < 6)      asm volatile("s_waitcnt vmcnt(12) lgkmcnt(0)\n\ts_barrier" ::: "memory");
    else if (c + 1 < 6) asm volatile("s_waitcnt vmcnt(8) lgkmcnt(0)\n\ts_barrier" ::: "memory");
    else                asm volatile("s_waitcnt vmcnt(0) lgkmcnt(0)\n\ts_barrier" ::: "memory");

    const short* AtB = &At[c & 3][0];
    short8 Af[8];
    #pragma unroll
    for (int ii = 0; ii < 8; ++ii) Af[ii] = *(const short8*)(AtB + aof[ii]);
    __builtin_amdgcn_s_setprio(1);
    #pragma unroll
    for (int ks = 0; ks < 2; ++ks)
      #pragma unroll
      for (int mf = 0; mf < 4; ++mf)
        #pragma unroll
        for (int nf = 0; nf < 4; ++nf)
          acc[mf][nf] = __builtin_amdgcn_mfma_f32_16x16x32_bf16(Af[mf * 2 + ks], Bcur[nf * 2 + ks], acc[mf][nf], 0, 0, 0);
    __builtin_amdgcn_s_setprio(0);
    #pragma unroll
    for (int ii = 0; ii < 8; ++ii) Bcur[ii] = Bnxt[ii];
  }

  #pragma unroll
  for (int mf = 0; mf < 4; ++mf)
    #pragma unroll
    for (int nf = 0; nf < 4; ++nf) {
      int n = nt * 128 + wc * 64 + nf * 16 + lm;
      float bias = bh[n];
      #pragma unroll
      for (int j = 0; j < 4; ++j) {
        int R = R0 + wr * 64 + mf * 16 + kg * 4 + j;
        float v = acc[mf][nf][j] + bias;
        v = v > 0.0f ? v : 0.0f;
        out[(size_t)R * 256 + n] = v;
        if ((R & (S_LEN - 1)) == (S_LEN - 1))
          out[HN_OFF + (R >> 12) * 256 + n] = v;
      }
    }
}

extern "C" void kernel_launch(void* const* d_in, const int* in_sizes, int n_in,
                              void* d_out, int out_size, void* d_ws, size_t ws_size,
                              hipStream_t stream) {
  const float* x  = (const float*)d_in[0];
  const float* Wu = (const float*)d_in[1];
  const float* bu = (const float*)d_in[2];
  const float* Wh = (const float*)d_in[3];
  const float* bh = (const float*)d_in[4];
  const float* H  = (const float*)d_in[5];
  float* out = (float*)d_out;

  char* ws = (char*)d_ws;
  short* cp  = (short*)(ws + 131072);              // 557056 B
  short* Hb  = (short*)(ws + 688128);              // 2097152 B
  short* wht = (short*)(ws + 2785280);             // 196608 B
  short* mx  = (short*)(ws + 2981888);             // 25165824 B

  k_prep<<<12744, 256, 0, stream>>>(x, Wu, bu, H, Wh, mx, cp, Hb, wht);
  k_conv<<<512,  256, 0, stream>>>(cp, Hb, mx);
  k_gemm2<<<512, 256, 0, stream>>>(mx, wht, bh, out);
}